// Round 12
// baseline (117.824 us; speedup 1.0000x reference)
//
#include <hip/hip_runtime.h>
#include <math.h>

// TeacherMLP fused forward.
// R12 = R11 with __launch_bounds__(1024) UNCAPPED (no min-waves arg).
// R9/R11 both failed with the bit-identical absmax 48.4375; the shared
// factor is launch_bounds(...,8) = 64-VGPR cap on the dual-pair body
// (needs ~52 free-running; R9's prefetch pushed past 64) => allocator
// spills inline-asm v2f PAIR operands => deterministic miscompile.
// R8 (single-pair, 32 VGPR) passed under the same cap; R10 (dual-pair,
// cap 128, measured 52 VGPR) passed. Fix: never cap VGPRs below what the
// asm-pair body needs.
// Experiment (unchanged from R11): split-K=4, 1024-thr blocks, 512 blocks;
// if VGPR <= 64 the HW runs 2 blocks/CU = 8 waves/SIMD at identical total
// instruction count. Latency model -> ~40-44us; structural -> ~51us.

typedef float v2f __attribute__((ext_vector_type(2)));

#define SC   2.885390081777927f      /* 2*log2(e): exp2(SC*z) = e^{2z} */
#define INV  (1.0f / 2.885390081777927f)
#define INV2PI 0.15915494309189535f
#define HS_CLAMP 32.0f               /* clamp on SC-prescaled activations */
#define C8   0.00390625f             /* 2^-8 */

__device__ __forceinline__ float fast_rcp(float x)  { return __builtin_amdgcn_rcpf(x); }
__device__ __forceinline__ float fast_exp2(float x) { return __builtin_amdgcn_exp2f(x); }
__device__ __forceinline__ v2f pk2(float a, float b) { v2f r; r.x = a; r.y = b; return r; }

// ---- hand-emitted VOP3P packed-f32 ----
__device__ __forceinline__ v2f pk_add(v2f a, v2f b) {
    v2f d; asm("v_pk_add_f32 %0, %1, %2" : "=v"(d) : "v"(a), "v"(b)); return d;
}
__device__ __forceinline__ v2f pk_mul(v2f a, v2f b) {
    v2f d; asm("v_pk_mul_f32 %0, %1, %2" : "=v"(d) : "v"(a), "v"(b)); return d;
}
__device__ __forceinline__ v2f pk_fma(v2f a, v2f b, v2f c) {
    v2f d; asm("v_pk_fma_f32 %0, %1, %2, %3" : "=v"(d) : "v"(a), "v"(b), "v"(c)); return d;
}
// d = a * broadcast(src1.lo) + c
__device__ __forceinline__ v2f pk_fma_lo(v2f a, v2f s, v2f c) {
    v2f d; asm("v_pk_fma_f32 %0, %1, %2, %3 op_sel_hi:[1,0,1]"
               : "=v"(d) : "v"(a), "v"(s), "v"(c)); return d;
}
// d = a * broadcast(src1.hi) + c
__device__ __forceinline__ v2f pk_fma_hi(v2f a, v2f s, v2f c) {
    v2f d; asm("v_pk_fma_f32 %0, %1, %2, %3 op_sel:[0,1,0] op_sel_hi:[1,1,1]"
               : "=v"(d) : "v"(a), "v"(s), "v"(c)); return d;
}
__device__ __forceinline__ v2f pk_exp(v2f t) {  // 2 HW exp2 into a pair
    v2f e; e.x = fast_exp2(t.x); e.y = fast_exp2(t.y); return e;
}
__device__ __forceinline__ v2f lo2(float4 w) { return pk2(w.x, w.y); }
__device__ __forceinline__ v2f hi2(float4 w) { return pk2(w.z, w.w); }

__global__ void weff_kernel(const float* __restrict__ W0, const int* __restrict__ I0,
                            const float* __restrict__ W1, const int* __restrict__ I1,
                            const float* __restrict__ W2, const int* __restrict__ I2,
                            float* __restrict__ ws) {
    int tid = blockIdx.x * blockDim.x + threadIdx.x;   // 0 .. 163839
    const float* W; const int* I; float* out; int outd; int e;
    if (tid < 65536)        { W = W0; I = I0; out = ws;          outd = 256; e = tid; }
    else if (tid < 131072)  { W = W1; I = I1; out = ws + 65536;  outd = 256; e = tid - 65536; }
    else if (tid < 163840)  { W = W2; I = I2; out = ws + 131072; outd = 128; e = tid - 131072; }
    else return;
    int o = e >> 8;       // out index (in-dim always 256)
    int i = e & 255;      // in index
    float w = W[e];       // coalesced (e = o*256 + i)
    int idx = I[e];
    // branchless atoms: [id, sin, tanh, square]
    float sn = __builtin_amdgcn_sinf(w * INV2PI);
    float th = 1.0f - 2.0f * fast_rcp(fast_exp2(w * SC) + 1.0f);
    float sq = w * w;
    float v = (idx == 1) ? sn : (idx == 2) ? th : (idx == 3) ? sq : w;
    // packed store: [i/4][o][i%4] -> main loop reads float4 of 4 K-values
    out[(i >> 2) * (outd * 4) + o * 4 + (i & 3)] = v;
}

// num/den of sum_{k=0..3} 1/B_k over 4 i-values, one row-pair packed.
// B = exp2(t-8) + 2^-8 = 2^-8 * (e^{2z}+1); shift folds into the t-fma.
struct ND { v2f n, d; };
__device__ __forceinline__ ND tree4(float4 pa, float4 pb, float4 w, v2f m8, v2f c8) {
    v2f h0 = pk2(pa.x, pa.y), h1 = pk2(pa.z, pa.w);
    v2f h2 = pk2(pb.x, pb.y), h3 = pk2(pb.z, pb.w);
    v2f wxy = lo2(w), wzw = hi2(w);
    v2f B0 = pk_add(pk_exp(pk_fma_lo(h0, wxy, m8)), c8);
    v2f B1 = pk_add(pk_exp(pk_fma_hi(h1, wxy, m8)), c8);
    v2f B2 = pk_add(pk_exp(pk_fma_lo(h2, wzw, m8)), c8);
    v2f B3 = pk_add(pk_exp(pk_fma_hi(h3, wzw, m8)), c8);
    v2f S1 = pk_add(B0, B1), P1 = pk_mul(B0, B1);
    v2f S2 = pk_add(B2, B3), P2 = pk_mul(B2, B3);
    ND r;
    r.n = pk_fma(S2, P1, pk_mul(S1, P2));
    r.d = pk_mul(P1, P2);
    return r;
}

// merge two 4-trees (8 i-values, one row-pair) with ONE rcp per row.
__device__ __forceinline__ v2f sig8_acc(ND a, ND b, v2f acc) {
    v2f num = pk_fma(b.n, a.d, pk_mul(a.n, b.d));
    v2f den = pk_mul(a.d, b.d);
    v2f rd;  rd.x = fast_rcp(den.x); rd.y = fast_rcp(den.y);
    return pk_fma(num, rd, acc);
}

__global__ __launch_bounds__(1024) void mlp_kernel(
    const float* __restrict__ x,  const float* __restrict__ b0,
    const float* __restrict__ b1, const float* __restrict__ b2,
    const float* __restrict__ ws, float* __restrict__ out) {
    const float4* We0 = (const float4*)ws;             // [64][256] packed [ic][o][4]
    const float4* We1 = (const float4*)(ws + 65536);   // [64][256]
    const float4* We2 = (const float4*)(ws + 131072);  // [64][128]

    __shared__ __align__(16) v2f hA0[256];      // pair0: rows (row0, row0+1)
    __shared__ __align__(16) v2f hA1[256];      // pair1: rows (row0+2, row0+3)
    __shared__ __align__(16) v2f hB0[256];
    __shared__ __align__(16) v2f hB1[256];
    __shared__ __align__(16) v2f partA[1024];   // split-K partials, pair 0
    __shared__ __align__(16) v2f partB[1024];   // pair 1

    const int t = threadIdx.x;     // 0..1023
    const int g = t >> 8;          // K-quarter 0..3 (wave-uniform)
    const int o = t & 255;         // neuron
    const int row0 = blockIdx.x * 4;

    const v2f m8 = pk2(-8.0f, -8.0f);
    const v2f c8 = pk2(C8, C8);

    // stage 4 input rows: thread (rs, o) loads row row0+rs.
    {
        const int rs = t >> 8;     // 0..3
        float xv = x[(row0 + rs) * 256 + o] * SC;
        xv = fminf(fmaxf(xv, -HS_CLAMP), HS_CLAMP);
        v2f* H = (rs & 2) ? hA1 : hA0;
        ((float*)(H + o))[rs & 1] = xv;
    }
    __syncthreads();

    // ---------------- layer 0: hA* -> hB* (split-K=4) ----------------
    {
        const float bias = b0[o];
        v2f acc0 = pk2(0.f, 0.f), acc1 = pk2(0.f, 0.f);
#pragma unroll 2
        for (int icc = 0; icc < 16; icc += 2) {
            int ic = g * 16 + icc;
            float4 w0 = We0[ic * 256 + o];
            float4 w1 = We0[(ic + 1) * 256 + o];
            const float4* hp0 = (const float4*)(hA0 + ic * 4);
            const float4* hp1 = (const float4*)(hA1 + ic * 4);
            ND r0 = tree4(hp0[0], hp0[1], w0, m8, c8);
            ND r1 = tree4(hp0[2], hp0[3], w1, m8, c8);
            acc0 = sig8_acc(r0, r1, acc0);
            ND r2 = tree4(hp1[0], hp1[1], w0, m8, c8);   // independent chain
            ND r3 = tree4(hp1[2], hp1[3], w1, m8, c8);
            acc1 = sig8_acc(r2, r3, acc1);
        }
        partA[g * 256 + o] = acc0;
        partB[g * 256 + o] = acc1;
        __syncthreads();
        // combine: thread (g,o) produces h for row row0+g at neuron o.
        const v2f* P = (g & 2) ? partB : partA;
        const int  ln = g & 1;
        float s = ((const float*)(P + o))[ln]
                + ((const float*)(P + 256 + o))[ln]
                + ((const float*)(P + 512 + o))[ln]
                + ((const float*)(P + 768 + o))[ln];
        float h = (256.0f - 0.0078125f * s + bias) * SC;   // 2^-7 undoes B-scale x2
        h = fminf(fmaxf(h, -HS_CLAMP), HS_CLAMP);
        v2f* H = (g & 2) ? hB1 : hB0;
        ((float*)(H + o))[ln] = h;
        __syncthreads();
    }

    // ---------------- layer 1: hB* -> hA* (split-K=4) ----------------
    {
        const float bias = b1[o];
        v2f acc0 = pk2(0.f, 0.f), acc1 = pk2(0.f, 0.f);
#pragma unroll 2
        for (int icc = 0; icc < 16; icc += 2) {
            int ic = g * 16 + icc;
            float4 w0 = We1[ic * 256 + o];
            float4 w1 = We1[(ic + 1) * 256 + o];
            const float4* hp0 = (const float4*)(hB0 + ic * 4);
            const float4* hp1 = (const float4*)(hB1 + ic * 4);
            ND r0 = tree4(hp0[0], hp0[1], w0, m8, c8);
            ND r1 = tree4(hp0[2], hp0[3], w1, m8, c8);
            acc0 = sig8_acc(r0, r1, acc0);
            ND r2 = tree4(hp1[0], hp1[1], w0, m8, c8);
            ND r3 = tree4(hp1[2], hp1[3], w1, m8, c8);
            acc1 = sig8_acc(r2, r3, acc1);
        }
        partA[g * 256 + o] = acc0;
        partB[g * 256 + o] = acc1;
        __syncthreads();
        const v2f* P = (g & 2) ? partB : partA;
        const int  ln = g & 1;
        float s = ((const float*)(P + o))[ln]
                + ((const float*)(P + 256 + o))[ln]
                + ((const float*)(P + 512 + o))[ln]
                + ((const float*)(P + 768 + o))[ln];
        float h = (256.0f - 0.0078125f * s + bias) * SC;
        h = fminf(fmaxf(h, -HS_CLAMP), HS_CLAMP);
        v2f* H = (g & 2) ? hA1 : hA0;
        ((float*)(H + o))[ln] = h;
        __syncthreads();
    }

    // ---------------- layer 2: hA* -> out (identity matmul, 8-way split-K) -
    {
        const int o2 = t & 127;
        const int q  = t >> 7;     // K-eighth 0..7
        v2f acc0 = pk2(0.f, 0.f), acc1 = pk2(0.f, 0.f);
#pragma unroll 4
        for (int icc = 0; icc < 8; icc++) {
            int ic = q * 8 + icc;
            float4 w = We2[ic * 128 + o2];
            const float4* hp0 = (const float4*)(hA0 + ic * 4);
            const float4* hp1 = (const float4*)(hA1 + ic * 4);
            float4 pa = hp0[0], pb = hp0[1];
            float4 qa = hp1[0], qb = hp1[1];
            v2f wxy = lo2(w), wzw = hi2(w);
            acc0 = pk_fma_lo(pk2(pa.x, pa.y), wxy, acc0);
            acc0 = pk_fma_hi(pk2(pa.z, pa.w), wxy, acc0);
            acc0 = pk_fma_lo(pk2(pb.x, pb.y), wzw, acc0);
            acc0 = pk_fma_hi(pk2(pb.z, pb.w), wzw, acc0);
            acc1 = pk_fma_lo(pk2(qa.x, qa.y), wxy, acc1);
            acc1 = pk_fma_hi(pk2(qa.z, qa.w), wxy, acc1);
            acc1 = pk_fma_lo(pk2(qb.x, qb.y), wzw, acc1);
            acc1 = pk_fma_hi(pk2(qb.z, qb.w), wzw, acc1);
        }
        partA[q * 128 + o2] = acc0;
        partB[q * 128 + o2] = acc1;
        __syncthreads();
        // 512 outputs (4 rows x 128), one per thread for t < 512.
        if (t < 512) {
            const int r  = t >> 7;        // 0..3 -> row row0 + r
            const int oo = t & 127;
            const v2f* prt = (r & 2) ? partB : partA;
            const int  ln  = r & 1;
            float s = 0.f;
#pragma unroll
            for (int q2 = 0; q2 < 8; q2++)
                s += ((const float*)(prt + q2 * 128 + oo))[ln];
            out[(row0 + r) * 128 + oo] = s * INV + b2[oo];  // undo SC prescale
        }
    }
}

extern "C" void kernel_launch(void* const* d_in, const int* in_sizes, int n_in,
                              void* d_out, int out_size, void* d_ws, size_t ws_size,
                              hipStream_t stream) {
    const float* x  = (const float*)d_in[0];
    const float* W0 = (const float*)d_in[1];
    const float* b0 = (const float*)d_in[2];
    const int*   I0 = (const int*)  d_in[3];
    const float* W1 = (const float*)d_in[4];
    const float* b1 = (const float*)d_in[5];
    const int*   I1 = (const int*)  d_in[6];
    const float* W2 = (const float*)d_in[7];
    const float* b2 = (const float*)d_in[8];
    const int*   I2 = (const int*)  d_in[9];
    float* ws  = (float*)d_ws;    // 163840 floats = 655360 B
    float* out = (float*)d_out;

    weff_kernel<<<640, 256, 0, stream>>>(W0, I0, W1, I1, W2, I2, ws);
    mlp_kernel<<<512, 1024, 0, stream>>>(x, b0, b1, b2, ws, out);
}